// Round 2
// baseline (12362.447 us; speedup 1.0000x reference)
//
#include <hip/hip_runtime.h>
#include <math.h>

#define SEQ 200
#define XROW 176   // 44 ptr + 128 enc + (closest,pred0,pred1) + 1 pad

__device__ __forceinline__ float sigmoidf_(float x) { return 1.0f / (1.0f + __expf(-x)); }

// ---------------- W_out transpose: WoT[90][256] ----------------
__global__ void transpose_wout(const float* __restrict__ W_out, float* __restrict__ WoT) {
    int c = blockIdx.x;      // 0..89
    int k = threadIdx.x;     // 0..255
    WoT[c * 256 + k] = W_out[k * 90 + c];
}

// ---------------- Encoder + layout transform ----------------
// grid: SEQ*32 blocks (t, 32-batch chunk), 256 threads. Writes Xg[t][b][0..171].
__global__ __launch_bounds__(256) void enc_kernel(
    const float* __restrict__ coords,
    const float* __restrict__ W_e1, const float* __restrict__ b_e1,
    const float* __restrict__ W_e2, const float* __restrict__ b_e2,
    float* __restrict__ Xg)
{
    __shared__ float C[32][89];
    __shared__ float H[32][2][65];
    __shared__ float W2[64][64];
    __shared__ float O[128][33];

    int t  = blockIdx.x >> 5;
    int bc = blockIdx.x & 31;
    int tid = threadIdx.x;

    for (int idx = tid; idx < 32 * 88; idx += 256) {
        int bl = idx / 88, j = idx - bl * 88;
        C[bl][j] = coords[((size_t)(bc * 32 + bl) * SEQ + t) * 88 + j];
    }
    for (int idx = tid; idx < 64 * 64; idx += 256)
        W2[idx >> 6][idx & 63] = W_e2[idx];
    __syncthreads();

    // phase A: per-team mean of relu(pts @ W_e1 + b_e1)
    {
        int b  = tid >> 3;            // 0..31
        int cq = (tid & 7) * 8;       // 8 cols per thread
        float w0[8], w1[8], bb[8];
#pragma unroll
        for (int j = 0; j < 8; j++) { w0[j] = W_e1[cq + j]; w1[j] = W_e1[64 + cq + j]; bb[j] = b_e1[cq + j]; }
        for (int tm = 0; tm < 2; tm++) {
            float a[8];
#pragma unroll
            for (int j = 0; j < 8; j++) a[j] = 0.f;
            for (int p = 0; p < 11; p++) {
                float x = C[b][(tm * 11 + p) * 4];
                float y = C[b][(tm * 11 + p) * 4 + 1];
#pragma unroll
                for (int j = 0; j < 8; j++) {
                    float h = fmaf(x, w0[j], fmaf(y, w1[j], bb[j]));
                    a[j] += fmaxf(h, 0.f);
                }
            }
#pragma unroll
            for (int j = 0; j < 8; j++) H[b][tm][cq + j] = a[j] * (1.0f / 11.0f);
        }
    }
    __syncthreads();

    // phase B: out = h_mean @ W_e2 + b_e2
    {
        int b  = tid >> 3;            // 0..31
        int tm = (tid >> 2) & 1;
        int ch = (tid & 3) * 16;
        float a[16];
#pragma unroll
        for (int c = 0; c < 16; c++) a[c] = 0.f;
        for (int k = 0; k < 64; k++) {
            float h = H[b][tm][k];
#pragma unroll
            for (int c = 0; c < 16; c++) a[c] = fmaf(h, W2[k][ch + c], a[c]);
        }
#pragma unroll
        for (int c = 0; c < 16; c++) O[tm * 64 + ch + c][b] = a[c] + b_e2[ch + c];
    }
    __syncthreads();

    // write enc rows 44..171 of Xg[t][b][.]
    for (int idx = tid; idx < 32 * 32; idx += 256) {
        int b = idx >> 5, rq = idx & 31;
        float4 v = make_float4(O[rq * 4][b], O[rq * 4 + 1][b], O[rq * 4 + 2][b], O[rq * 4 + 3][b]);
        *(float4*)&Xg[((size_t)t * 1024 + bc * 32 + b) * XROW + 44 + rq * 4] = v;
    }
    // write ptr rows 0..43
    for (int idx = tid; idx < 32 * 11; idx += 256) {
        int b = idx / 11, jq = idx - b * 11;
        int j0 = jq * 4;
        float4 v;
        v.x = C[b][((j0 + 0) >> 1) * 4 + ((j0 + 0) & 1)];
        v.y = C[b][((j0 + 1) >> 1) * 4 + ((j0 + 1) & 1)];
        v.z = C[b][((j0 + 2) >> 1) * 4 + ((j0 + 2) & 1)];
        v.w = C[b][((j0 + 3) >> 1) * 4 + ((j0 + 3) & 1)];
        *(float4*)&Xg[((size_t)t * 1024 + bc * 32 + b) * XROW + j0] = v;
    }
}

// ---------------- Per-step kernel ----------------
// grid 256: bi = blockIdx.x&15 (64-batch tile), hj = blockIdx.x>>4 (16-hidden tile)
// Wave g (=tid>>6) computes gate g's 16 cols; lane (=tid&63) is the batch index.
__global__ __launch_bounds__(256) void step_kernel(
    int t, const float* __restrict__ Xg,
    const float* __restrict__ hx_in, float* __restrict__ hx_out, float* __restrict__ cx,
    const float* __restrict__ W_ih, const float* __restrict__ b_ih,
    const float* __restrict__ W_hh, const float* __restrict__ b_hh,
    const float* __restrict__ WoT, const float* __restrict__ b_out,
    const float* __restrict__ pitch, float* __restrict__ d_out)
{
    __shared__ float XT[64][180];   // [batch][k], stride 180 (45 odd -> bank-optimal b128 cols)
    __shared__ float G[4096];       // gate exchange / out-proj partials
    __shared__ float WoL[256][8];   // out-proj weights, k-major
    __shared__ float predL[64][2];

    int tid = threadIdx.x;
    int bi = blockIdx.x & 15, hj = blockIdx.x >> 4;
    int bg0 = bi * 64;

    // ---- stage XT[b][0..175] from Xg (t<SEQ) ----
    if (t < SEQ) {
        for (int idx = tid; idx < 64 * 44; idx += 256) {
            int b = idx / 44, kq = idx - b * 44;
            float4 v = *(const float4*)&Xg[((size_t)t * 1024 + bg0 + b) * XROW + kq * 4];
            *(float4*)&XT[b][kq * 4] = v;
        }
    }
    // ---- stage WoL[k][c]: cols 0..5 = out slice, 6..7 = pred cols 88,89 ----
    {
        int c = tid >> 5, k0 = (tid & 31) * 8;
        int col = (c < 6) ? (hj * 6 + c) : (88 + (c - 6));
        if (col < 90) {
            float4 a  = *(const float4*)&WoT[col * 256 + k0];
            float4 bq = *(const float4*)&WoT[col * 256 + k0 + 4];
            WoL[k0 + 0][c] = a.x;  WoL[k0 + 1][c] = a.y;
            WoL[k0 + 2][c] = a.z;  WoL[k0 + 3][c] = a.w;
            WoL[k0 + 4][c] = bq.x; WoL[k0 + 5][c] = bq.y;
            WoL[k0 + 6][c] = bq.z; WoL[k0 + 7][c] = bq.w;
        } else {
#pragma unroll
            for (int j = 0; j < 8; j++) WoL[k0 + j][c] = 0.f;
        }
    }
    __syncthreads();

    // ---- out-projection partials: out_{t-1} = hx_{t-1} @ W_out cols ----
    {
        int b = tid & 63, kq = tid >> 6;
        float ao[8];
#pragma unroll
        for (int c = 0; c < 8; c++) ao[c] = 0.f;
        if (t > 0) {
            const float* hxp = hx_in + bg0 + b;
#pragma unroll 4
            for (int k = kq * 64; k < kq * 64 + 64; k++) {
                float h = hxp[(size_t)k << 10];
                float4 w0 = *(const float4*)&WoL[k][0];
                float4 w1 = *(const float4*)&WoL[k][4];
                ao[0] = fmaf(h, w0.x, ao[0]); ao[1] = fmaf(h, w0.y, ao[1]);
                ao[2] = fmaf(h, w0.z, ao[2]); ao[3] = fmaf(h, w0.w, ao[3]);
                ao[4] = fmaf(h, w1.x, ao[4]); ao[5] = fmaf(h, w1.y, ao[5]);
                ao[6] = fmaf(h, w1.z, ao[6]); ao[7] = fmaf(h, w1.w, ao[7]);
            }
        }
#pragma unroll
        for (int c = 0; c < 8; c++) G[(kq * 64 + b) * 8 + c] = ao[c];
    }
    __syncthreads();
    if (tid < 128) {
        int b = tid >> 1, hf = tid & 1;
#pragma unroll
        for (int j = 0; j < 4; j++) {
            int c = hf * 4 + j;
            float s = G[(0 * 64 + b) * 8 + c] + G[(1 * 64 + b) * 8 + c] +
                      G[(2 * 64 + b) * 8 + c] + G[(3 * 64 + b) * 8 + c];
            int col = (c < 6) ? (hj * 6 + c) : (88 + (c - 6));
            if (t > 0 && col < 90) {
                float v = (s + b_out[col]) * pitch[col & 1];
                if (c < 6) d_out[((size_t)(bg0 + b) * SEQ + (t - 1)) * 90 + col] = v;
                else predL[b][c - 6] = v;
            } else if (c >= 6) {
                predL[b][c - 6] = 0.f;
            }
        }
    }
    __syncthreads();

    if (t >= SEQ) return;

    // ---- closest distance; patch XT[b][172..174] ----
    if (tid < 64) {
        int b = tid;
        float p0 = predL[b][0], p1 = predL[b][1];
        float m = 1e30f;
#pragma unroll
        for (int p = 0; p < 22; p++) {
            float dx = p0 - XT[b][2 * p];
            float dy = p1 - XT[b][2 * p + 1];
            m = fminf(m, fmaf(dx, dx, dy * dy));
        }
        XT[b][172] = sqrtf(m);
        XT[b][173] = p0;
        XT[b][174] = p1;
    }
    __syncthreads();

    // ---- GEMM: wave g, lane = batch; 16 cols/wave, W streamed from L2 ----
    int g = tid >> 6, lane = tid & 63;
    int C0 = g * 256 + hj * 16;
    float acc[16];
#pragma unroll
    for (int c = 0; c < 16; c++) acc[c] = 0.f;

    {   // part 1: k in [0,172) from XT, W_ih
        const float* Wc = W_ih + C0;
        for (int kg = 0; kg < 43; kg++) {
            float4 xv = *(const float4*)&XT[lane][kg * 4];
            const float* Wk = Wc + (size_t)kg * 4096;
#pragma unroll
            for (int j = 0; j < 4; j++) {
                float x = (&xv.x)[j];
                float4 w0 = *(const float4*)(Wk + (size_t)j * 1024);
                float4 w1 = *(const float4*)(Wk + (size_t)j * 1024 + 4);
                float4 w2 = *(const float4*)(Wk + (size_t)j * 1024 + 8);
                float4 w3 = *(const float4*)(Wk + (size_t)j * 1024 + 12);
                acc[0]  = fmaf(x, w0.x, acc[0]);  acc[1]  = fmaf(x, w0.y, acc[1]);
                acc[2]  = fmaf(x, w0.z, acc[2]);  acc[3]  = fmaf(x, w0.w, acc[3]);
                acc[4]  = fmaf(x, w1.x, acc[4]);  acc[5]  = fmaf(x, w1.y, acc[5]);
                acc[6]  = fmaf(x, w1.z, acc[6]);  acc[7]  = fmaf(x, w1.w, acc[7]);
                acc[8]  = fmaf(x, w2.x, acc[8]);  acc[9]  = fmaf(x, w2.y, acc[9]);
                acc[10] = fmaf(x, w2.z, acc[10]); acc[11] = fmaf(x, w2.w, acc[11]);
                acc[12] = fmaf(x, w3.x, acc[12]); acc[13] = fmaf(x, w3.y, acc[13]);
                acc[14] = fmaf(x, w3.z, acc[14]); acc[15] = fmaf(x, w3.w, acc[15]);
            }
        }
        // tail: k = 172..174 (closest, pred0, pred1)
        float4 xv = *(const float4*)&XT[lane][172];
#pragma unroll
        for (int j = 0; j < 3; j++) {
            float x = (&xv.x)[j];
            const float* Wk = Wc + (size_t)(172 + j) * 1024;
            float4 w0 = *(const float4*)(Wk);
            float4 w1 = *(const float4*)(Wk + 4);
            float4 w2 = *(const float4*)(Wk + 8);
            float4 w3 = *(const float4*)(Wk + 12);
            acc[0]  = fmaf(x, w0.x, acc[0]);  acc[1]  = fmaf(x, w0.y, acc[1]);
            acc[2]  = fmaf(x, w0.z, acc[2]);  acc[3]  = fmaf(x, w0.w, acc[3]);
            acc[4]  = fmaf(x, w1.x, acc[4]);  acc[5]  = fmaf(x, w1.y, acc[5]);
            acc[6]  = fmaf(x, w1.z, acc[6]);  acc[7]  = fmaf(x, w1.w, acc[7]);
            acc[8]  = fmaf(x, w2.x, acc[8]);  acc[9]  = fmaf(x, w2.y, acc[9]);
            acc[10] = fmaf(x, w2.z, acc[10]); acc[11] = fmaf(x, w2.w, acc[11]);
            acc[12] = fmaf(x, w3.x, acc[12]); acc[13] = fmaf(x, w3.y, acc[13]);
            acc[14] = fmaf(x, w3.z, acc[14]); acc[15] = fmaf(x, w3.w, acc[15]);
        }
    }
    {   // part 2: k in [0,256): x = hx from global (L2), W_hh
        const float* Wc2 = W_hh + C0;
        const float* hxp = hx_in + bg0 + lane;
#pragma unroll 4
        for (int k = 0; k < 256; k++) {
            float x = hxp[(size_t)k << 10];
            const float* Wk = Wc2 + (size_t)k * 1024;
            float4 w0 = *(const float4*)(Wk);
            float4 w1 = *(const float4*)(Wk + 4);
            float4 w2 = *(const float4*)(Wk + 8);
            float4 w3 = *(const float4*)(Wk + 12);
            acc[0]  = fmaf(x, w0.x, acc[0]);  acc[1]  = fmaf(x, w0.y, acc[1]);
            acc[2]  = fmaf(x, w0.z, acc[2]);  acc[3]  = fmaf(x, w0.w, acc[3]);
            acc[4]  = fmaf(x, w1.x, acc[4]);  acc[5]  = fmaf(x, w1.y, acc[5]);
            acc[6]  = fmaf(x, w1.z, acc[6]);  acc[7]  = fmaf(x, w1.w, acc[7]);
            acc[8]  = fmaf(x, w2.x, acc[8]);  acc[9]  = fmaf(x, w2.y, acc[9]);
            acc[10] = fmaf(x, w2.z, acc[10]); acc[11] = fmaf(x, w2.w, acc[11]);
            acc[12] = fmaf(x, w3.x, acc[12]); acc[13] = fmaf(x, w3.y, acc[13]);
            acc[14] = fmaf(x, w3.z, acc[14]); acc[15] = fmaf(x, w3.w, acc[15]);
        }
    }

    // ---- exchange gates, LSTM pointwise ----
#pragma unroll
    for (int c = 0; c < 16; c++) G[(g * 16 + c) * 64 + lane] = acc[c];
    __syncthreads();
#pragma unroll
    for (int q = 0; q < 4; q++) {
        int id = q * 256 + tid;
        int b = id & 63, hl = id >> 6;        // hl 0..15
        int gb = hj * 16 + hl;
        float iv = G[(0 * 16 + hl) * 64 + b] + b_ih[gb]       + b_hh[gb];
        float fv = G[(1 * 16 + hl) * 64 + b] + b_ih[256 + gb] + b_hh[256 + gb];
        float gv = G[(2 * 16 + hl) * 64 + b] + b_ih[512 + gb] + b_hh[512 + gb];
        float ov = G[(3 * 16 + hl) * 64 + b] + b_ih[768 + gb] + b_hh[768 + gb];
        size_t cidx = (size_t)gb * 1024 + bg0 + b;
        float c_old = cx[cidx];
        float c_new = fmaf(sigmoidf_(fv), c_old, sigmoidf_(iv) * tanhf(gv));
        cx[cidx] = c_new;
        hx_out[cidx] = sigmoidf_(ov) * tanhf(c_new);
    }
}

extern "C" void kernel_launch(void* const* d_in, const int* in_sizes, int n_in,
                              void* d_out, int out_size, void* d_ws, size_t ws_size,
                              hipStream_t stream) {
    const float* coords = (const float*)d_in[0];
    const float* pitch  = (const float*)d_in[1];
    const float* W_e1   = (const float*)d_in[2];
    const float* b_e1   = (const float*)d_in[3];
    const float* W_e2   = (const float*)d_in[4];
    const float* b_e2   = (const float*)d_in[5];
    const float* W_ih   = (const float*)d_in[6];
    const float* b_ih   = (const float*)d_in[7];
    const float* W_hh   = (const float*)d_in[8];
    const float* b_hh   = (const float*)d_in[9];
    const float* W_out  = (const float*)d_in[10];
    const float* b_out  = (const float*)d_in[11];
    float* out = (float*)d_out;
    float* ws  = (float*)d_ws;

    // ws layout (floats):
    float* hxA = ws;                 // 262144
    float* cxb = ws + 262144;        // 262144
    float* hxB = ws + 524288;        // 262144
    float* WoT = ws + 786432;        // 23040
    float* Xg  = ws + 809472;        // 200*1024*176 = 36,044,800
    // total 36,854,272 floats ~= 147.4 MB

    hipMemsetAsync(ws, 0, (size_t)2 * 262144 * sizeof(float), stream);  // hxA + cx

    transpose_wout<<<90, 256, 0, stream>>>(W_out, WoT);
    enc_kernel<<<SEQ * 32, 256, 0, stream>>>(coords, W_e1, b_e1, W_e2, b_e2, Xg);

    for (int t = 0; t <= SEQ; t++) {
        const float* hin = (t & 1) ? hxB : hxA;
        float* hout      = (t & 1) ? hxA : hxB;
        step_kernel<<<256, 256, 0, stream>>>(t, Xg, hin, hout, cxb,
                                             W_ih, b_ih, W_hh, b_hh, WoT, b_out, pitch, out);
    }
}

// Round 3
// 7763.260 us; speedup vs baseline: 1.5924x; 1.5924x over previous
//
#include <hip/hip_runtime.h>
#include <math.h>

#define SEQ 200

__device__ __forceinline__ float sigmoidf_(float x) { return 1.0f / (1.0f + __expf(-x)); }

// ---------------- Wo8 pack: Wo8[cj][k][8] = W_out cols {cj*6+0..5, 88, 89} ----------------
__global__ void wo8_pack(const float* __restrict__ W_out, float* __restrict__ Wo8) {
    int cj = blockIdx.x;        // 0..15
    int k  = threadIdx.x;       // 0..255
#pragma unroll
    for (int c8 = 0; c8 < 8; c8++) {
        int col = (c8 < 6) ? (cj * 6 + c8) : (82 + c8);   // 6,7 -> 88,89
        Wo8[((size_t)cj * 256 + k) * 8 + c8] = (col < 90) ? W_out[k * 90 + col] : 0.f;
    }
}

// ---------------- Encoder: writes Xk[t][row 0..171][1024 b] (k-major) ----------------
__global__ __launch_bounds__(256) void enc_kernel(
    const float* __restrict__ coords,
    const float* __restrict__ W_e1, const float* __restrict__ b_e1,
    const float* __restrict__ W_e2, const float* __restrict__ b_e2,
    float* __restrict__ Xk)
{
    __shared__ float C[32][89];
    __shared__ float H[32][2][65];
    __shared__ float W2[64][64];
    __shared__ float O[128][33];

    int t  = blockIdx.x >> 5;
    int bc = blockIdx.x & 31;
    int tid = threadIdx.x;

    for (int idx = tid; idx < 32 * 88; idx += 256) {
        int bl = idx / 88, j = idx - bl * 88;
        C[bl][j] = coords[((size_t)(bc * 32 + bl) * SEQ + t) * 88 + j];
    }
    for (int idx = tid; idx < 64 * 64; idx += 256)
        W2[idx >> 6][idx & 63] = W_e2[idx];
    __syncthreads();

    // phase A: per-team mean of relu(pts @ W_e1 + b_e1)
    {
        int b  = tid >> 3;            // 0..31
        int cq = (tid & 7) * 8;
        float w0[8], w1[8], bb[8];
#pragma unroll
        for (int j = 0; j < 8; j++) { w0[j] = W_e1[cq + j]; w1[j] = W_e1[64 + cq + j]; bb[j] = b_e1[cq + j]; }
        for (int tm = 0; tm < 2; tm++) {
            float a[8];
#pragma unroll
            for (int j = 0; j < 8; j++) a[j] = 0.f;
            for (int p = 0; p < 11; p++) {
                float x = C[b][(tm * 11 + p) * 4];
                float y = C[b][(tm * 11 + p) * 4 + 1];
#pragma unroll
                for (int j = 0; j < 8; j++) {
                    float h = fmaf(x, w0[j], fmaf(y, w1[j], bb[j]));
                    a[j] += fmaxf(h, 0.f);
                }
            }
#pragma unroll
            for (int j = 0; j < 8; j++) H[b][tm][cq + j] = a[j] * (1.0f / 11.0f);
        }
    }
    __syncthreads();

    // phase B: out = h_mean @ W_e2 + b_e2
    {
        int b  = tid >> 3;
        int tm = (tid >> 2) & 1;
        int ch = (tid & 3) * 16;
        float a[16];
#pragma unroll
        for (int c = 0; c < 16; c++) a[c] = 0.f;
        for (int k = 0; k < 64; k++) {
            float h = H[b][tm][k];
#pragma unroll
            for (int c = 0; c < 16; c++) a[c] = fmaf(h, W2[k][ch + c], a[c]);
        }
#pragma unroll
        for (int c = 0; c < 16; c++) O[tm * 64 + ch + c][b] = a[c] + b_e2[ch + c];
    }
    __syncthreads();

    float* xt = Xk + (size_t)t * 172 * 1024 + bc * 32;
    // enc rows 44..171
    for (int idx = tid; idx < 128 * 32; idx += 256) {
        int r = idx >> 5, b = idx & 31;
        xt[(size_t)(44 + r) * 1024 + b] = O[r][b];
    }
    // ptr rows 0..43 (player x/y interleaved)
    for (int idx = tid; idx < 44 * 32; idx += 256) {
        int j = idx >> 5, b = idx & 31;
        xt[(size_t)j * 1024 + b] = C[b][(j >> 1) * 4 + (j & 1)];
    }
}

// ---------------- Per-step kernel ----------------
// grid 256: bi = blockIdx&15 (64-batch tile), cj = blockIdx>>4 (16-hidden tile)
// Wave w = gate w; lane = batch. W comes via wave-uniform scalar loads (SMEM pipe),
// x via coalesced k-major b32 loads (VMEM pipe), FMAs with SGPR W operand.
__global__ __launch_bounds__(256) void step_kernel(
    int t, const float* __restrict__ Xk,
    const float* __restrict__ hx_in, float* __restrict__ hx_out, float* __restrict__ cx,
    const float* __restrict__ W_ih, const float* __restrict__ W_hh,
    const float* __restrict__ b_ih, const float* __restrict__ b_hh,
    const float* __restrict__ Wo8, const float* __restrict__ b_out,
    const float* __restrict__ pitch, float* __restrict__ d_out)
{
    __shared__ float P[4][64][9];
    __shared__ float predL[64][2];
    __shared__ float G[4][16][64];

    const int tid  = threadIdx.x;
    const int lane = tid & 63;
    const int wv   = __builtin_amdgcn_readfirstlane(tid >> 6);   // wave id 0..3 (uniform)
    const int bi = blockIdx.x & 15, cj = blockIdx.x >> 4;
    const int bg0 = bi * 64;

    // ---- Phase A: out-projection partials (k-quarter per wave, 8 cols) ----
    if (t > 0) {
        float a[8];
#pragma unroll
        for (int c = 0; c < 8; c++) a[c] = 0.f;
        const float* hq = hx_in + (size_t)(wv * 64) * 1024 + bg0 + lane;
        const float* wo = Wo8 + ((size_t)cj * 256 + wv * 64) * 8;
#pragma unroll 4
        for (int k = 0; k < 64; k++) {
            float x = hq[(size_t)k * 1024];
#pragma unroll
            for (int c = 0; c < 8; c++) a[c] = fmaf(x, wo[k * 8 + c], a[c]);
        }
#pragma unroll
        for (int c = 0; c < 8; c++) P[wv][lane][c] = a[c];
    }
    __syncthreads();   // S1

    // ---- reduce partials -> d_out[t-1] cols + predL ----
    {
        int b = tid & 63, cq = tid >> 6;
        if (t > 0) {
#pragma unroll
            for (int rr = 0; rr < 2; rr++) {
                int c8 = cq + rr * 4;
                float s = P[0][b][c8] + P[1][b][c8] + P[2][b][c8] + P[3][b][c8];
                int col = (c8 < 6) ? (cj * 6 + c8) : (82 + c8);
                if (col < 90) {
                    float v = (s + b_out[col]) * pitch[col & 1];
                    if (c8 < 6) d_out[(size_t)(bg0 + b) * (SEQ * 90) + (size_t)(t - 1) * 90 + col] = v;
                    else        predL[b][c8 - 6] = v;
                }
            }
        } else if (cq >= 2) {
            predL[b][cq - 2] = 0.f;
        }
    }
    __syncthreads();   // S2

    if (t >= SEQ) return;

    // ---- closest distance (per-wave redundant, all in registers) ----
    const float* xbase = Xk + (size_t)t * 172 * 1024 + bg0 + lane;
    float p0 = predL[lane][0], p1 = predL[lane][1];
    float m = 1e30f;
#pragma unroll
    for (int p = 0; p < 22; p++) {
        float dx = p0 - xbase[(size_t)(2 * p) * 1024];
        float dy = p1 - xbase[(size_t)(2 * p + 1) * 1024];
        m = fminf(m, fmaf(dx, dx, dy * dy));
    }
    float xc = sqrtf(m);

    // ---- GEMM: gate wv, 16 cols cj*16.., lane = batch ----
    const int c0 = wv * 256 + cj * 16;
    float acc[16];
#pragma unroll
    for (int i = 0; i < 16; i++) acc[i] = 0.f;

    {   // L1: k = 0..171 (x-features)
        const float* Wg = W_ih + c0;
#pragma unroll 4
        for (int k = 0; k < 172; k++) {
            float x = xbase[(size_t)k * 1024];
            const float* wk = Wg + (size_t)k * 1024;
#pragma unroll
            for (int i = 0; i < 16; i++) acc[i] = fmaf(x, wk[i], acc[i]);
        }
    }
    {   // L2: k = 172..174 (closest, pred0, pred1) from registers
        const float* wk = W_ih + (size_t)172 * 1024 + c0;
#pragma unroll
        for (int i = 0; i < 16; i++) acc[i] = fmaf(xc, wk[i], acc[i]);
        wk += 1024;
#pragma unroll
        for (int i = 0; i < 16; i++) acc[i] = fmaf(p0, wk[i], acc[i]);
        wk += 1024;
#pragma unroll
        for (int i = 0; i < 16; i++) acc[i] = fmaf(p1, wk[i], acc[i]);
    }
    {   // L3: k = 0..255 (hx part)
        const float* hxb = hx_in + bg0 + lane;
        const float* Wh = W_hh + c0;
#pragma unroll 4
        for (int k = 0; k < 256; k++) {
            float x = hxb[(size_t)k * 1024];
            const float* wk = Wh + (size_t)k * 1024;
#pragma unroll
            for (int i = 0; i < 16; i++) acc[i] = fmaf(x, wk[i], acc[i]);
        }
    }

    // ---- exchange gates, LSTM pointwise ----
#pragma unroll
    for (int i = 0; i < 16; i++) G[wv][i][lane] = acc[i];
    __syncthreads();   // S3
#pragma unroll
    for (int r = 0; r < 4; r++) {
        int h  = wv * 4 + r;            // 0..15
        int hg = cj * 16 + h;           // global hidden index
        float iv = G[0][h][lane] + b_ih[hg]       + b_hh[hg];
        float fv = G[1][h][lane] + b_ih[256 + hg] + b_hh[256 + hg];
        float gv = G[2][h][lane] + b_ih[512 + hg] + b_hh[512 + hg];
        float ov = G[3][h][lane] + b_ih[768 + hg] + b_hh[768 + hg];
        size_t idx = (size_t)hg * 1024 + bg0 + lane;
        float c_old = cx[idx];
        float c_new = fmaf(sigmoidf_(fv), c_old, sigmoidf_(iv) * tanhf(gv));
        cx[idx] = c_new;
        hx_out[idx] = sigmoidf_(ov) * tanhf(c_new);
    }
}

extern "C" void kernel_launch(void* const* d_in, const int* in_sizes, int n_in,
                              void* d_out, int out_size, void* d_ws, size_t ws_size,
                              hipStream_t stream) {
    const float* coords = (const float*)d_in[0];
    const float* pitch  = (const float*)d_in[1];
    const float* W_e1   = (const float*)d_in[2];
    const float* b_e1   = (const float*)d_in[3];
    const float* W_e2   = (const float*)d_in[4];
    const float* b_e2   = (const float*)d_in[5];
    const float* W_ih   = (const float*)d_in[6];
    const float* b_ih   = (const float*)d_in[7];
    const float* W_hh   = (const float*)d_in[8];
    const float* b_hh   = (const float*)d_in[9];
    const float* W_out  = (const float*)d_in[10];
    const float* b_out  = (const float*)d_in[11];
    float* out = (float*)d_out;
    float* ws  = (float*)d_ws;

    // ws layout (floats):
    float* cxb = ws;                 // 262144  (cx, zeroed)
    float* hxA = ws + 262144;        // 262144  (zeroed; t=0 input)
    float* hxB = ws + 524288;        // 262144
    float* Wo8 = ws + 786432;        // 32768
    float* Xk  = ws + 819200;        // 200*172*1024 = 35,225,600
    // total ~36.0M floats ~= 144.2 MB

    hipMemsetAsync(ws, 0, (size_t)524288 * sizeof(float), stream);   // cx + hxA

    wo8_pack<<<16, 256, 0, stream>>>(W_out, Wo8);
    enc_kernel<<<SEQ * 32, 256, 0, stream>>>(coords, W_e1, b_e1, W_e2, b_e2, Xk);

    for (int t = 0; t <= SEQ; t++) {
        const float* hin = (t & 1) ? hxB : hxA;
        float* hout      = (t & 1) ? hxA : hxB;
        step_kernel<<<256, 256, 0, stream>>>(t, Xk, hin, hout, cxb,
                                             W_ih, W_hh, b_ih, b_hh, Wo8, b_out, pitch, out);
    }
}